// Round 1
// baseline (3043.410 us; speedup 1.0000x reference)
//
#include <hip/hip_runtime.h>
#include <math.h>

#define NGROUP 4
#define BATCH  4096
#define TSTEPS 128

// ---------------- workspace layout (float offsets) ----------------
#define WI0T_OFF 0               // 4*48*64*4  = 49152  : Wi0t[g][k][u][s]
#define WH0T_OFF 49152           // 4*64*64*4  = 65536  : Wh0t[g][k][u][s]
#define B0T_OFF  114688          // 4*64*4     = 1024   : b0t[g][u][s]
#define KAL_OFF  115712          // 4*128*48   = 24576  : per (g,t): K[24], Sinv[16], logdet[1]
#define LL_OFF   147456          // 4*128*4096 = 2097152
#define XN_OFF   (147456 + 2097152)   // 4*128*4096*6 = 12582912
// total = 14,827,520 floats = 59.3 MB

// ---------------- shared-memory layout (float offsets) ----------------
#define SM_WH0   0               // 16384
#define SM_WE1   16384           // 912
#define SM_BE1   17296           // 48
#define SM_WE2   17344           // 2304
#define SM_BE2   19648           // 48
#define SM_WI1   19696           // 1024
#define SM_WH1   20720           // 64
#define SM_B1L   20784           // 16
#define SM_B0T   20800           // 256
#define SM_WAVE  21056
#define PER_WAVE 1312            // bufA 384 | bufB 384 | h0b 512 | h1b 32
#define SMEM_FLOATS (21056 + 8*1312)   // 31552 floats = 126208 bytes

__device__ __forceinline__ float fast_sig(float x) {
    return __builtin_amdgcn_rcpf(1.0f + __expf(-x));
}
__device__ __forceinline__ float fast_tanh(float x) {
    float ax = fabsf(x);
    float t  = __expf(-2.0f * ax);
    float r  = (1.0f - t) * __builtin_amdgcn_rcpf(1.0f + t);
    return copysignf(r, x);
}

// ============ prep 1: transpose LSTM0 weights into [k][u][gate4] ============
__global__ void nkf_prep_tr(const float* __restrict__ Wi0, const float* __restrict__ Wh0,
                            const float* __restrict__ b0, float* __restrict__ ws) {
    int idx = blockIdx.x * 256 + threadIdx.x;
    if (idx < 49152) {
        int g = idx / 12288, r2 = idx % 12288;
        int k = r2 >> 8, u = (r2 & 255) >> 2, s = r2 & 3;
        ws[WI0T_OFF + idx] = Wi0[g * 12288 + k * 256 + s * 64 + u];
    } else if (idx < 49152 + 65536) {
        int j = idx - 49152;
        int g = j / 16384, r2 = j % 16384;
        int k = r2 >> 8, u = (r2 & 255) >> 2, s = r2 & 3;
        ws[WH0T_OFF + j] = Wh0[g * 16384 + k * 256 + s * 64 + u];
    } else if (idx < 49152 + 65536 + 1024) {
        int j = idx - 114688;
        int g = j >> 8, r2 = j & 255;
        int u = r2 >> 2, s = r2 & 3;
        ws[B0T_OFF + j] = b0[g * 256 + s * 64 + u];
    }
}

// ============ prep 2: data-independent Kalman gain sequence ============
__global__ void nkf_prep_kal(const float* __restrict__ Q_log, const float* __restrict__ R_log,
                             float* __restrict__ ws) {
    int g = blockIdx.x * blockDim.x + threadIdx.x;
    if (g >= NGROUP) return;
    float Qd[6], Rd[4];
#pragma unroll
    for (int i = 0; i < 6; i++) Qd[i] = expf(Q_log[g * 6 + i]);
#pragma unroll
    for (int i = 0; i < 4; i++) Rd[i] = expf(R_log[i]);
    float P[6][6];
#pragma unroll
    for (int i = 0; i < 6; i++)
#pragma unroll
        for (int j = 0; j < 6; j++) P[i][j] = (i == j) ? 1000.0f : 0.0f;
    float* ko = ws + KAL_OFF + (size_t)g * (TSTEPS * 48);

#pragma unroll 1
    for (int t = 0; t < TSTEPS; t++) {
        float FP[6][6], Pp[6][6];
#pragma unroll
        for (int i = 0; i < 6; i++)
#pragma unroll
            for (int j = 0; j < 6; j++) FP[i][j] = P[i][j] + ((i < 3) ? P[i + 3][j] : 0.0f);
#pragma unroll
        for (int i = 0; i < 6; i++)
#pragma unroll
            for (int j = 0; j < 6; j++) Pp[i][j] = FP[i][j] + ((j < 3) ? FP[i][j + 3] : 0.0f);
#pragma unroll
        for (int i = 0; i < 6; i++) Pp[i][i] += Qd[i];

        float S[4][4];
#pragma unroll
        for (int i = 0; i < 4; i++)
#pragma unroll
            for (int j = 0; j < 4; j++) S[i][j] = Pp[i][j] + ((i == j) ? Rd[i] : 0.0f);

        // Cholesky S = L L^T
        float L[4][4];
#pragma unroll
        for (int j = 0; j < 4; j++) {
            float d = S[j][j];
            for (int k = 0; k < j; k++) d -= L[j][k] * L[j][k];
            L[j][j] = sqrtf(d);
            float inv = 1.0f / L[j][j];
            for (int i = j + 1; i < 4; i++) {
                float s2 = S[i][j];
                for (int k = 0; k < j; k++) s2 -= L[i][k] * L[j][k];
                L[i][j] = s2 * inv;
            }
        }
        float logdet = 2.0f * (logf(L[0][0]) + logf(L[1][1]) + logf(L[2][2]) + logf(L[3][3]));

        // Li = L^-1 (lower)
        float Li[4][4];
#pragma unroll
        for (int j = 0; j < 4; j++) {
            Li[j][j] = 1.0f / L[j][j];
            for (int i = j + 1; i < 4; i++) {
                float s2 = 0.0f;
                for (int k = j; k < i; k++) s2 += L[i][k] * Li[k][j];
                Li[i][j] = -s2 / L[i][i];
            }
        }
        // Sinv = Li^T Li
        float Si[4][4];
#pragma unroll
        for (int i = 0; i < 4; i++)
#pragma unroll
            for (int j = 0; j < 4; j++) {
                float s2 = 0.0f;
                for (int k = (i > j ? i : j); k < 4; k++) s2 += Li[k][i] * Li[k][j];
                Si[i][j] = s2;
            }
        // K = Pp[:, :4] * Sinv
        float K[6][4];
#pragma unroll
        for (int i = 0; i < 6; i++)
#pragma unroll
            for (int o = 0; o < 4; o++) {
                float s2 = 0.0f;
                for (int m = 0; m < 4; m++) s2 += Pp[i][m] * Si[m][o];
                K[i][o] = s2;
            }
        // store
#pragma unroll
        for (int i = 0; i < 6; i++)
#pragma unroll
            for (int o = 0; o < 4; o++) ko[t * 48 + i * 4 + o] = K[i][o];
#pragma unroll
        for (int i = 0; i < 4; i++)
#pragma unroll
            for (int j = 0; j < 4; j++) ko[t * 48 + 24 + i * 4 + j] = Si[i][j];
        ko[t * 48 + 40] = logdet;

        // P = Pp - K * Pp[:4,:]
        float Pn[6][6];
#pragma unroll
        for (int i = 0; i < 6; i++)
#pragma unroll
            for (int j = 0; j < 6; j++) {
                float s2 = Pp[i][j];
                for (int m = 0; m < 4; m++) s2 -= K[i][m] * Pp[m][j];
                Pn[i][j] = s2;
            }
#pragma unroll
        for (int i = 0; i < 6; i++)
#pragma unroll
            for (int j = 0; j < 6; j++) P[i][j] = Pn[i][j];
    }
}

// ============ main: 256 blocks x 512 threads; wave = 8 chains of one group ============
__global__ __launch_bounds__(512, 2) void nkf_main(
    const float* __restrict__ z, const float* __restrict__ x0,
    const float* __restrict__ We1, const float* __restrict__ be1,
    const float* __restrict__ We2, const float* __restrict__ be2,
    const float* __restrict__ Wi1, const float* __restrict__ Wh1,
    const float* __restrict__ b1l, const float* __restrict__ ws,
    float* __restrict__ ll_out, float* __restrict__ xn_out) {
    extern __shared__ float sm[];
    const int tid  = threadIdx.x;
    const int g    = blockIdx.x >> 6;
    const int bblk = blockIdx.x & 63;
    const int w    = tid >> 6;
    const int l    = tid & 63;

    {   // cooperative weight staging
        const float* wh0 = ws + WH0T_OFF + g * 16384;
        for (int i = tid; i < 16384; i += 512) sm[SM_WH0 + i] = wh0[i];
        for (int i = tid; i < 912; i += 512) sm[SM_WE1 + i] = We1[i];
        if (tid < 48) sm[SM_BE1 + tid] = be1[tid];
        for (int i = tid; i < 2304; i += 512) sm[SM_WE2 + i] = We2[i];
        if (tid < 48) sm[SM_BE2 + tid] = be2[tid];
        const float* wi1p = Wi1 + g * 1024;
        for (int i = tid; i < 1024; i += 512) sm[SM_WI1 + i] = wi1p[i];
        if (tid < 64) sm[SM_WH1 + tid] = Wh1[g * 64 + tid];
        if (tid < 16) sm[SM_B1L + tid] = b1l[g * 16 + tid];
        const float* b0tp = ws + B0T_OFF + g * 256;
        if (tid < 256) sm[SM_B0T + tid] = b0tp[tid];
    }
    __syncthreads();

    float* bufA = sm + SM_WAVE + w * PER_WAVE;
    float* bufB = bufA + 384;
    float* h0b  = bufB + 384;
    float* h1b  = h0b + 512;

    const int c  = l >> 3, r = l & 7;
    const int bq = bblk * 64 + w * 8 + c;   // batch index for chain-phases

    float c0v[8];
#pragma unroll
    for (int i = 0; i < 8; i++) c0v[i] = 0.0f;
#pragma unroll
    for (int i = 0; i < 8; i++) h0b[l * 8 + i] = 0.0f;
    if (l < 32) h1b[l] = 0.0f;
    float c1u = 0.0f;
    float xr[6] = {0, 0, 0, 0, 0, 0};
    float zb[4] = {0, 0, 0, 0};
    if (r == 0) {
#pragma unroll
        for (int i = 0; i < 6; i++) xr[i] = x0[bq * 6 + i];
    }
    const float*  kal = ws + KAL_OFF + (size_t)g * (TSTEPS * 48);
    const float4* wi0 = (const float4*)(ws + WI0T_OFF) + (size_t)g * 3072;

    for (int t = 0; t < TSTEPS; ++t) {
        // ---------- feats (lane r==0 of each chain) ----------
        if (r == 0) {
            const float* zp = z + ((size_t)bq * TSTEPS + t) * 4;
            zb[0] = zp[0]; zb[1] = zp[1]; zb[2] = zp[2]; zb[3] = zp[3];
            bufA[0 * 8 + c] = zb[0]; bufA[1 * 8 + c] = zb[1];
            bufA[2 * 8 + c] = zb[2]; bufA[3 * 8 + c] = zb[3];
#pragma unroll
            for (int i = 0; i < 6; i++) bufA[(4 + i) * 8 + c] = xr[i];
            float i0 = zb[0] - xr[0], i1 = zb[1] - xr[1], i2 = zb[2] - xr[2], i3 = zb[3] - xr[3];
            bufA[10 * 8 + c] = i0; bufA[11 * 8 + c] = i1;
            bufA[12 * 8 + c] = i2; bufA[13 * 8 + c] = i3;
            bufA[14 * 8 + c] = sqrtf(i0 * i0 + i1 * i1 + i2 * i2 + i3 * i3);
            bufA[15 * 8 + c] = sqrtf(xr[0] * xr[0] + xr[1] * xr[1] + xr[2] * xr[2]);
            bufA[16 * 8 + c] = sqrtf(xr[3] * xr[3] + xr[4] * xr[4] + xr[5] * xr[5]);
            bufA[17 * 8 + c] = (float)t / 100.0f;
            bufA[18 * 8 + c] = 1.0f;
        }
        asm volatile("" ::: "memory");
        // ---------- E1: lanes 0..47 -> e1[j][c] ----------
        if (l < 48) {
            float acc[8];
            float bb = sm[SM_BE1 + l];
#pragma unroll
            for (int i = 0; i < 8; i++) acc[i] = bb;
            for (int k = 0; k < 19; k++) {
                float  wv = sm[SM_WE1 + k * 48 + l];
                float4 f0 = *(const float4*)&bufA[k * 8];
                float4 f1 = *(const float4*)&bufA[k * 8 + 4];
                acc[0] += wv * f0.x; acc[1] += wv * f0.y; acc[2] += wv * f0.z; acc[3] += wv * f0.w;
                acc[4] += wv * f1.x; acc[5] += wv * f1.y; acc[6] += wv * f1.z; acc[7] += wv * f1.w;
            }
#pragma unroll
            for (int i = 0; i < 8; i++) acc[i] = fmaxf(acc[i], 0.0f);
            float4 o0 = {acc[0], acc[1], acc[2], acc[3]};
            float4 o1 = {acc[4], acc[5], acc[6], acc[7]};
            *(float4*)&bufB[l * 8]     = o0;
            *(float4*)&bufB[l * 8 + 4] = o1;
        }
        asm volatile("" ::: "memory");
        // ---------- E2: lanes 0..47 -> e2[j][c] ----------
        if (l < 48) {
            float acc[8];
            float bb = sm[SM_BE2 + l];
#pragma unroll
            for (int i = 0; i < 8; i++) acc[i] = bb;
            for (int k = 0; k < 48; k++) {
                float  wv = sm[SM_WE2 + k * 48 + l];
                float4 f0 = *(const float4*)&bufB[k * 8];
                float4 f1 = *(const float4*)&bufB[k * 8 + 4];
                acc[0] += wv * f0.x; acc[1] += wv * f0.y; acc[2] += wv * f0.z; acc[3] += wv * f0.w;
                acc[4] += wv * f1.x; acc[5] += wv * f1.y; acc[6] += wv * f1.z; acc[7] += wv * f1.w;
            }
#pragma unroll
            for (int i = 0; i < 8; i++) acc[i] = fmaxf(acc[i], 0.0f);
            float4 o0 = {acc[0], acc[1], acc[2], acc[3]};
            float4 o1 = {acc[4], acc[5], acc[6], acc[7]};
            *(float4*)&bufA[l * 8]     = o0;
            *(float4*)&bufA[l * 8 + 4] = o1;
        }
        asm volatile("" ::: "memory");
        // ---------- LSTM0 gates: lane = unit, 8 chains blocked ----------
        float ac0[8], ac1[8], ac2[8], ac3[8];
        {
            float4 bb = *(const float4*)&sm[SM_B0T + l * 4];
#pragma unroll
            for (int i = 0; i < 8; i++) { ac0[i] = bb.x; ac1[i] = bb.y; ac2[i] = bb.z; ac3[i] = bb.w; }
        }
#pragma unroll 2
        for (int k = 0; k < 48; k++) {
            float4 wv = wi0[k * 64 + l];
            const float4 e0 = *(const float4*)&bufA[k * 8];
            const float4 e1 = *(const float4*)&bufA[k * 8 + 4];
            float ev[8] = {e0.x, e0.y, e0.z, e0.w, e1.x, e1.y, e1.z, e1.w};
#pragma unroll
            for (int i = 0; i < 8; i++) {
                ac0[i] += wv.x * ev[i];
                ac1[i] += wv.y * ev[i];
                ac2[i] += wv.z * ev[i];
                ac3[i] += wv.w * ev[i];
            }
        }
#pragma unroll 2
        for (int k = 0; k < 64; k++) {
            float4 wv = *(const float4*)&sm[SM_WH0 + (k * 64 + l) * 4];
            const float4 h0_ = *(const float4*)&h0b[k * 8];
            const float4 h1_ = *(const float4*)&h0b[k * 8 + 4];
            float hv[8] = {h0_.x, h0_.y, h0_.z, h0_.w, h1_.x, h1_.y, h1_.z, h1_.w};
#pragma unroll
            for (int i = 0; i < 8; i++) {
                ac0[i] += wv.x * hv[i];
                ac1[i] += wv.y * hv[i];
                ac2[i] += wv.z * hv[i];
                ac3[i] += wv.w * hv[i];
            }
        }
        float hn[8];
#pragma unroll
        for (int i = 0; i < 8; i++) {
            float iv = ac0[i], fv = ac1[i], gv = ac2[i], ov = ac3[i];
            float cn = fast_sig(fv) * c0v[i] + fast_sig(iv) * fast_tanh(gv);
            c0v[i] = cn;
            hn[i]  = fast_sig(ov) * fast_tanh(cn);
        }
        asm volatile("" ::: "memory");
        {
            float4 o0 = {hn[0], hn[1], hn[2], hn[3]};
            float4 o1 = {hn[4], hn[5], hn[6], hn[7]};
            *(float4*)&h0b[l * 8]     = o0;
            *(float4*)&h0b[l * 8 + 4] = o1;
        }
        asm volatile("" ::: "memory");
        // ---------- LSTM1: chain c = l>>3, gates q0=r, q1=r+8 ----------
        float ga  = sm[SM_B1L + r];
        float gb2 = sm[SM_B1L + r + 8];
#pragma unroll 4
        for (int k = 0; k < 64; k++) {
            float hv = h0b[k * 8 + c];
            ga  += sm[SM_WI1 + k * 16 + r] * hv;
            gb2 += sm[SM_WI1 + k * 16 + r + 8] * hv;
        }
#pragma unroll
        for (int j = 0; j < 4; j++) {
            float hv = h1b[j * 8 + c];
            ga  += sm[SM_WH1 + j * 16 + r] * hv;
            gb2 += sm[SM_WH1 + j * 16 + r + 8] * hv;
        }
        float fO = __shfl_xor(ga, 4, 64);
        float oO = __shfl_xor(gb2, 4, 64);
        asm volatile("" ::: "memory");
        if (r < 4) {
            float cn = fast_sig(fO) * c1u + fast_sig(ga) * fast_tanh(gb2);
            c1u = cn;
            h1b[r * 8 + c] = fast_sig(oO) * fast_tanh(cn);
        }
        asm volatile("" ::: "memory");
        // ---------- Kalman measurement update (lane r==0) ----------
        if (r == 0) {
            float logp = h1b[0 * 8 + c];
            float a0 = h1b[1 * 8 + c], a1 = h1b[2 * 8 + c], a2 = h1b[3 * 8 + c];
            float xp[6];
            xp[0] = xr[0] + xr[3] + 0.5f * a0;   // DT = 1
            xp[1] = xr[1] + xr[4] + 0.5f * a1;
            xp[2] = xr[2] + xr[5] + 0.5f * a2;
            xp[3] = xr[3] + a0;
            xp[4] = xr[4] + a1;
            xp[5] = xr[5] + a2;
            float y0 = zb[0] - xp[0], y1 = zb[1] - xp[1], y2 = zb[2] - xp[2], y3 = zb[3] - xp[3];
            const float* kt = kal + t * 48;
            float xn[6];
#pragma unroll
            for (int i = 0; i < 6; i++)
                xn[i] = xp[i] + kt[i * 4 + 0] * y0 + kt[i * 4 + 1] * y1 +
                        kt[i * 4 + 2] * y2 + kt[i * 4 + 3] * y3;
            float sy0 = kt[24] * y0 + kt[25] * y1 + kt[26] * y2 + kt[27] * y3;
            float sy1 = kt[28] * y0 + kt[29] * y1 + kt[30] * y2 + kt[31] * y3;
            float sy2 = kt[32] * y0 + kt[33] * y1 + kt[34] * y2 + kt[35] * y3;
            float sy3 = kt[36] * y0 + kt[37] * y1 + kt[38] * y2 + kt[39] * y3;
            float quad = y0 * sy0 + y1 * sy1 + y2 * sy2 + y3 * sy3;
            float llv  = logp - 0.5f * (quad + kt[40]);
            size_t base = ((size_t)(g * TSTEPS + t)) * BATCH + bq;
            ll_out[base] = llv;
            float* xo = xn_out + base * 6;
#pragma unroll
            for (int i = 0; i < 6; i++) { xo[i] = xn[i]; xr[i] = xn[i]; }
        }
    }
}

// ============ argmax over groups + gather output ============
__global__ void nkf_gather(const float* __restrict__ ws, float* __restrict__ out) {
    int idx = blockIdx.x * 256 + threadIdx.x;   // t*BATCH + b
    if (idx >= TSTEPS * BATCH) return;
    const float* llp = ws + LL_OFF;
    float best = llp[idx];
    int   bg   = 0;
#pragma unroll
    for (int g2 = 1; g2 < 4; g2++) {
        float v = llp[(size_t)g2 * (TSTEPS * BATCH) + idx];
        if (v > best) { best = v; bg = g2; }
    }
    const float* xp = ws + XN_OFF + ((size_t)bg * (TSTEPS * BATCH) + idx) * 6;
    float* o = out + (size_t)idx * 6;
#pragma unroll
    for (int i = 0; i < 6; i++) o[i] = xp[i];
}

extern "C" void kernel_launch(void* const* d_in, const int* in_sizes, int n_in,
                              void* d_out, int out_size, void* d_ws, size_t ws_size,
                              hipStream_t stream) {
    const float* z   = (const float*)d_in[0];
    const float* x0  = (const float*)d_in[1];
    const float* We1 = (const float*)d_in[2];
    const float* be1 = (const float*)d_in[3];
    const float* We2 = (const float*)d_in[4];
    const float* be2 = (const float*)d_in[5];
    const float* Wi0 = (const float*)d_in[6];
    const float* Wh0 = (const float*)d_in[7];
    const float* b0  = (const float*)d_in[8];
    const float* Wi1 = (const float*)d_in[9];
    const float* Wh1 = (const float*)d_in[10];
    const float* b1l = (const float*)d_in[11];
    const float* Ql  = (const float*)d_in[12];
    const float* Rl  = (const float*)d_in[13];
    float* ws  = (float*)d_ws;
    float* out = (float*)d_out;

    hipFuncSetAttribute((const void*)nkf_main,
                        hipFuncAttributeMaxDynamicSharedMemorySize, SMEM_FLOATS * 4);

    nkf_prep_tr<<<(115712 + 255) / 256, 256, 0, stream>>>(Wi0, Wh0, b0, ws);
    nkf_prep_kal<<<1, 64, 0, stream>>>(Ql, Rl, ws);
    nkf_main<<<256, 512, SMEM_FLOATS * 4, stream>>>(z, x0, We1, be1, We2, be2,
                                                    Wi1, Wh1, b1l, ws,
                                                    ws + LL_OFF, ws + XN_OFF);
    nkf_gather<<<2048, 256, 0, stream>>>(ws, out);
}